// Round 9
// baseline (1215.655 us; speedup 1.0000x reference)
//
#include <hip/hip_runtime.h>
#include <hip/hip_bf16.h>
#include <math.h>

#define DEV __device__ __forceinline__

DEV float sigmoidf_(float x) { return 1.0f / (1.0f + __expf(-x)); }

#define R10(OP) OP(0) OP(1) OP(2) OP(3) OP(4) OP(5) OP(6) OP(7) OP(8) OP(9)
#define R11(OP) R10(OP) OP(10)

// dot of sA[base..base+9] with hO scalars (sA entries are wave-uniform)
#define DOT_O(base) (sA[(base)+0]*hO0 + sA[(base)+1]*hO1 + sA[(base)+2]*hO2 + sA[(base)+3]*hO3 \
                   + sA[(base)+4]*hO4 + sA[(base)+5]*hO5 + sA[(base)+6]*hO6 + sA[(base)+7]*hO7 \
                   + sA[(base)+8]*hO8 + sA[(base)+9]*hO9)
#define DOT_D(base) (sA[(base)+0]*hD0 + sA[(base)+1]*hD1 + sA[(base)+2]*hD2 + sA[(base)+3]*hD3 \
                   + sA[(base)+4]*hD4 + sA[(base)+5]*hD5 + sA[(base)+6]*hD6 + sA[(base)+7]*hD7 \
                   + sA[(base)+8]*hD8 + sA[(base)+9]*hD9 + sA[(base)+10]*hD10)

DEV float gstep(float x, float h, const float* k, const float* rk, const float* bb) {
  const float z  = sigmoidf_(fmaf(x, k[0], bb[0]) + fmaf(h, rk[0], bb[3]));
  const float r  = sigmoidf_(fmaf(x, k[1], bb[1]) + fmaf(h, rk[1], bb[4]));
  const float hh = tanhf(fmaf(x, k[2], bb[2]) + r * fmaf(h, rk[2], bb[5]));
  return z * h + (1.f - z) * hh;
}

// 3 tiny sequential bidirectional GRU chains + softmax + gather -> tp[3][60]
__global__ void __launch_bounds__(64, 1)
temporal_kernel(const float* __restrict__ T, const float* __restrict__ GK,
                const float* __restrict__ GRK, const float* __restrict__ GB,
                const float* __restrict__ WO, const int* __restrict__ IDX,
                float* __restrict__ tp) {
  const int i = threadIdx.x;
  __shared__ float fb[3][75];
  __shared__ float gg[3][75];
  if (i < 3) {
    float k0[3], k1[3], rk0[3], rk1[3];
#pragma unroll
    for (int q = 0; q < 3; ++q) {
      k0[q]  = GK[i * 6 + q];      k1[q]  = GK[i * 6 + 3 + q];
      rk0[q] = GRK[i * 6 + q];     rk1[q] = GRK[i * 6 + 3 + q];
    }
    const float* B0 = GB + i * 12;
    const float* B1 = GB + i * 12 + 6;
    float h = 0.f;
    for (int s = 0; s < 75; ++s) { h = gstep(T[i * 75 + s], h, k0, rk0, B0); fb[i][s] = h; }
    h = 0.f;
    for (int s = 0; s < 75; ++s) { h = gstep(fb[i][74 - s], h, k1, rk1, B1); gg[i][s] = h; }
    const float wo = WO[i];
    float mx = -1e30f;
    for (int s = 0; s < 75; ++s) mx = fmaxf(mx, gg[i][s] * wo);
    float sum = 0.f;
    for (int s = 0; s < 75; ++s) { const float e = __expf(gg[i][s] * wo - mx); fb[i][s] = e; sum += e; }
    const float inv = 1.f / sum;
    for (int j = 0; j < 60; ++j) tp[i * 60 + j] = fb[i][IDX[j]] * inv;
  }
}

// 4 waves per 256-thread block; wave w owns batch blockIdx.x*4+w with a
// PRIVATE LDS slice (no inter-wave sharing -> zero __syncthreads in the hot
// path; same-wave LDS RAW is ordered by compiler lgkmcnt). This packs 16
// waves/CU (4 WGs x 4 waves) where single-wave WGs plateaued at ~7/CU.
//   per-wave slice: sm[0..1919] O-stage / D+R-stage / score stash; sA[484].
__global__ void __launch_bounds__(256, 4) ggnn_main(
    const float* __restrict__ X, const float* __restrict__ A,
    const float* __restrict__ WgR, const float* __restrict__ bgR,
    const float* __restrict__ WgO, const float* __restrict__ bgO,
    const float* __restrict__ WgD, const float* __restrict__ bgD,
    const float* __restrict__ WzR, const float* __restrict__ WrR,
    const float* __restrict__ WmR, const float* __restrict__ bmR,
    const float* __restrict__ WzO, const float* __restrict__ WrO,
    const float* __restrict__ WmO, const float* __restrict__ bmO,
    const float* __restrict__ WzD, const float* __restrict__ WrD,
    const float* __restrict__ WmD, const float* __restrict__ bmD,
    const float* __restrict__ W1R, const float* __restrict__ b1R, const float* __restrict__ W2R,
    const float* __restrict__ W1O, const float* __restrict__ b1O, const float* __restrict__ W2O,
    const float* __restrict__ W1D, const float* __restrict__ b1D, const float* __restrict__ W2D,
    const float* __restrict__ tp, int B, float* __restrict__ out) {
  const int w = threadIdx.x >> 6;   // wave 0..3
  const int c = threadIdx.x & 63;   // lane = feature column
  const int b = blockIdx.x * 4 + w;

  __shared__ __align__(16) float smemAll[4 * 1920];
  __shared__ float sAAll[4 * 484];
  float* sm = smemAll + w * 1920;
  const float* sA = sAAll + w * 484;

  if (b >= B) return;

  const float* Xb = X + (size_t)b * 880;
  const float* Ab = A + (size_t)b * 484;
  for (int t = c; t < 880; t += 64) sm[t] = Xb[t];
  { float* sAw = sAAll + w * 484;
    for (int t = c; t < 484; t += 64) sAw[t] = Ab[t]; }

  // ---------------- phase 0: h = tanh(Xg @ Wg + bg) ----------------
  float hR;
#define DECLHO(i) float hO##i;
  R10(DECLHO)
#undef DECLHO
#define DECLHD(i) float hD##i;
  R11(DECLHD)
#undef DECLHD
  {
    float aR = bgR[c], cO = bgO[c], cD = bgD[c];
#pragma unroll 4
    for (int k = 0; k < 40; ++k) {
      const float x = sm[k];
      aR = fmaf(x, WgR[k * 64 + c], aR);
      cO = fmaf(x, WgO[k * 64 + c], cO);
      cD = fmaf(x, WgD[k * 64 + c], cD);
    }
    hR = tanhf(aR);
#define DECLAO(i) float aO##i = cO;
    R10(DECLAO)
#undef DECLAO
#define DECLAD(i) float aD##i = cD;
    R11(DECLAD)
#undef DECLAD
#pragma unroll 2
    for (int k = 0; k < 30; ++k) {
      const float wo_ = WgO[(40 + k) * 64 + c];
      const float wd_ = WgD[(40 + k) * 64 + c];
#define AOSTEP(i) aO##i = fmaf(sm[(1 + i) * 40 + 10 + k], wo_, aO##i);
      R10(AOSTEP)
#undef AOSTEP
#define ADSTEP(i) aD##i = fmaf(sm[(11 + i) * 40 + 10 + k], wd_, aD##i);
      R11(ADSTEP)
#undef ADSTEP
    }
#define TANHO(i) hO##i = tanhf(aO##i);
    R10(TANHO)
#undef TANHO
#define TANHD(i) hD##i = tanhf(aD##i);
    R11(TANHD)
#undef TANHD
  }

  // ---------------- 3 GRU iterations ----------------
  for (int it = 0; it < 3; ++it) {
    // snapshot messages that depend on OLD hO (gate O overwrites hO)
    const float nR = DOT_O(1);
#define DECLND(i) const float nD##i = DOT_O((11 + i) * 22 + 1);
    R11(DECLND)
#undef DECLND

    // ---- phase A: gate O (10 rows, K=192), region sm[0..1919] ----
#define STAGEO(i) sm[i * 192 + c] = hO##i; \
                  sm[i * 192 + 64 + c] = sA[(1 + i) * 22] * hR; \
                  sm[i * 192 + 128 + c] = DOT_D((1 + i) * 22 + 11);
    R10(STAGEO)
#undef STAGEO
    {
#define DECLZR(i) float az##i = 0.f, ar##i = 0.f;
      R10(DECLZR)
#undef DECLZR
#pragma unroll 2
      for (int k4 = 0; k4 < 192; k4 += 4) {
        const float wa0 = WzO[(k4 + 0) * 64 + c], wa1 = WzO[(k4 + 1) * 64 + c];
        const float wa2 = WzO[(k4 + 2) * 64 + c], wa3 = WzO[(k4 + 3) * 64 + c];
        const float wb0 = WrO[(k4 + 0) * 64 + c], wb1 = WrO[(k4 + 1) * 64 + c];
        const float wb2 = WrO[(k4 + 2) * 64 + c], wb3 = WrO[(k4 + 3) * 64 + c];
#define MSTEP(i) { const float4 v = *reinterpret_cast<const float4*>(&sm[i * 192 + k4]); \
        az##i = fmaf(v.x, wa0, az##i); az##i = fmaf(v.y, wa1, az##i); \
        az##i = fmaf(v.z, wa2, az##i); az##i = fmaf(v.w, wa3, az##i); \
        ar##i = fmaf(v.x, wb0, ar##i); ar##i = fmaf(v.y, wb1, ar##i); \
        ar##i = fmaf(v.z, wb2, ar##i); ar##i = fmaf(v.w, wb3, ar##i); }
        R10(MSTEP)
#undef MSTEP
      }
#define SIGZR(i) const float z##i = sigmoidf_(az##i); const float r##i = sigmoidf_(ar##i);
      R10(SIGZR)
#undef SIGZR
#define STAGEHR(i) sm[i * 192 + c] = hO##i * r##i;
      R10(STAGEHR)
#undef STAGEHR
#define DECLAM(i) float am##i = bmO[c];
      R10(DECLAM)
#undef DECLAM
#pragma unroll 2
      for (int k4 = 0; k4 < 192; k4 += 4) {
        const float w0 = WmO[(k4 + 0) * 64 + c], w1 = WmO[(k4 + 1) * 64 + c];
        const float w2 = WmO[(k4 + 2) * 64 + c], w3 = WmO[(k4 + 3) * 64 + c];
#define MSTEP(i) { const float4 v = *reinterpret_cast<const float4*>(&sm[i * 192 + k4]); \
        am##i = fmaf(v.x, w0, am##i); am##i = fmaf(v.y, w1, am##i); \
        am##i = fmaf(v.z, w2, am##i); am##i = fmaf(v.w, w3, am##i); }
        R10(MSTEP)
#undef MSTEP
      }
#define UPDO(i) hO##i = (1.f - z##i) * hO##i + z##i * tanhf(am##i);
      R10(UPDO)
#undef UPDO
    }

    // ---- phase B: gates D (11 rows, K=128, sm[0..1407]) + R (sm[1408..1535]) ----
#define STAGEDD(i) sm[i * 128 + c] = hD##i; \
                   sm[i * 128 + 64 + c] = nD##i;
    R11(STAGEDD)
#undef STAGEDD
    sm[1408 + c] = hR;
    sm[1472 + c] = nR;
    {
#define DECLZR(i) float az##i = 0.f, ar##i = 0.f;
      R11(DECLZR)
#undef DECLZR
      float azR = 0.f, arR = 0.f;
#pragma unroll 2
      for (int k4 = 0; k4 < 128; k4 += 4) {
        const float wa0 = WzD[(k4 + 0) * 64 + c], wa1 = WzD[(k4 + 1) * 64 + c];
        const float wa2 = WzD[(k4 + 2) * 64 + c], wa3 = WzD[(k4 + 3) * 64 + c];
        const float wb0 = WrD[(k4 + 0) * 64 + c], wb1 = WrD[(k4 + 1) * 64 + c];
        const float wb2 = WrD[(k4 + 2) * 64 + c], wb3 = WrD[(k4 + 3) * 64 + c];
#define MSTEP(i) { const float4 v = *reinterpret_cast<const float4*>(&sm[i * 128 + k4]); \
        az##i = fmaf(v.x, wa0, az##i); az##i = fmaf(v.y, wa1, az##i); \
        az##i = fmaf(v.z, wa2, az##i); az##i = fmaf(v.w, wa3, az##i); \
        ar##i = fmaf(v.x, wb0, ar##i); ar##i = fmaf(v.y, wb1, ar##i); \
        ar##i = fmaf(v.z, wb2, ar##i); ar##i = fmaf(v.w, wb3, ar##i); }
        R11(MSTEP)
#undef MSTEP
        const float wza0 = WzR[(k4 + 0) * 64 + c], wza1 = WzR[(k4 + 1) * 64 + c];
        const float wza2 = WzR[(k4 + 2) * 64 + c], wza3 = WzR[(k4 + 3) * 64 + c];
        const float wra0 = WrR[(k4 + 0) * 64 + c], wra1 = WrR[(k4 + 1) * 64 + c];
        const float wra2 = WrR[(k4 + 2) * 64 + c], wra3 = WrR[(k4 + 3) * 64 + c];
        const float4 vr = *reinterpret_cast<const float4*>(&sm[1408 + k4]);
        azR = fmaf(vr.x, wza0, azR); azR = fmaf(vr.y, wza1, azR);
        azR = fmaf(vr.z, wza2, azR); azR = fmaf(vr.w, wza3, azR);
        arR = fmaf(vr.x, wra0, arR); arR = fmaf(vr.y, wra1, arR);
        arR = fmaf(vr.z, wra2, arR); arR = fmaf(vr.w, wra3, arR);
      }
#define SIGZR(i) const float z##i = sigmoidf_(az##i); const float r##i = sigmoidf_(ar##i);
      R11(SIGZR)
#undef SIGZR
      const float zR_ = sigmoidf_(azR);
      const float rR_ = sigmoidf_(arR);
#define STAGEHR(i) sm[i * 128 + c] = hD##i * r##i;
      R11(STAGEHR)
#undef STAGEHR
      sm[1408 + c] = hR * rR_;
#define DECLAM(i) float am##i = bmD[c];
      R11(DECLAM)
#undef DECLAM
      float amR = bmR[c];
#pragma unroll 2
      for (int k4 = 0; k4 < 128; k4 += 4) {
        const float w0 = WmD[(k4 + 0) * 64 + c], w1 = WmD[(k4 + 1) * 64 + c];
        const float w2 = WmD[(k4 + 2) * 64 + c], w3 = WmD[(k4 + 3) * 64 + c];
#define MSTEP(i) { const float4 v = *reinterpret_cast<const float4*>(&sm[i * 128 + k4]); \
        am##i = fmaf(v.x, w0, am##i); am##i = fmaf(v.y, w1, am##i); \
        am##i = fmaf(v.z, w2, am##i); am##i = fmaf(v.w, w3, am##i); }
        R11(MSTEP)
#undef MSTEP
        const float wm0 = WmR[(k4 + 0) * 64 + c], wm1 = WmR[(k4 + 1) * 64 + c];
        const float wm2 = WmR[(k4 + 2) * 64 + c], wm3 = WmR[(k4 + 3) * 64 + c];
        const float4 vr = *reinterpret_cast<const float4*>(&sm[1408 + k4]);
        amR = fmaf(vr.x, wm0, amR); amR = fmaf(vr.y, wm1, amR);
        amR = fmaf(vr.z, wm2, amR); amR = fmaf(vr.w, wm3, amR);
      }
#define UPDD(i) hD##i = (1.f - z##i) * hD##i + z##i * tanhf(am##i);
      R11(UPDD)
#undef UPDD
      hR = (1.f - zR_) * hR + zR_ * tanhf(amR);
    }
  }

  // ---------------- scores ----------------
  sm[c] = hR;
#define STASH_O(i) sm[(1 + i) * 64 + c] = hO##i;
  R10(STASH_O)
#undef STASH_O
#define STASH_D(i) sm[(11 + i) * 64 + c] = hD##i;
  R11(STASH_D)
#undef STASH_D

  const int g = c >> 4;    // row-group 0..3
  const int c1 = c & 15;   // hidden-1 column
  float pR = 0.f, pO = 0.f, pD = 0.f;
  for (int rr = g; rr < 22; rr += 4) {
    const float* W1; const float* b1; const float* W2;
    if (rr == 0)      { W1 = W1R; b1 = b1R; W2 = W2R; }
    else if (rr < 11) { W1 = W1O; b1 = b1O; W2 = W2O; }
    else              { W1 = W1D; b1 = b1D; W2 = W2D; }
    float a = b1[c1];
#pragma unroll 8
    for (int kk = 0; kk < 64; ++kk) {
      const int k = (kk + (g << 4)) & 63;  // stagger to dodge LDS bank aliasing
      a = fmaf(sm[rr * 64 + k], W1[k * 16 + c1], a);
    }
    const float t = tanhf(a) * W2[c1];
    if (rr == 0) pR += t;
    else if (rr < 11) pO += t;
    else pD += t;
  }
#pragma unroll
  for (int off = 32; off >= 1; off >>= 1) {
    pR += __shfl_xor(pR, off, 64);
    pO += __shfl_xor(pO, off, 64);
    pD += __shfl_xor(pD, off, 64);
  }
  if (c < 60) {
    out[(size_t)b * 60 + c] = pR * tp[c] + pO * tp[60 + c] + pD * tp[120 + c];
  }
}

extern "C" void kernel_launch(void* const* d_in, const int* in_sizes, int n_in,
                              void* d_out, int out_size, void* d_ws, size_t ws_size,
                              hipStream_t stream) {
  const float* X   = (const float*)d_in[0];
  const float* A   = (const float*)d_in[1];
  const float* WgR = (const float*)d_in[2];
  const float* bgR = (const float*)d_in[3];
  const float* WgO = (const float*)d_in[4];
  const float* bgO = (const float*)d_in[5];
  const float* WgD = (const float*)d_in[6];
  const float* bgD = (const float*)d_in[7];
  const float* WzR = (const float*)d_in[8];
  const float* WrR = (const float*)d_in[9];
  const float* WmR = (const float*)d_in[10];
  const float* bmR = (const float*)d_in[11];
  const float* WzO = (const float*)d_in[12];
  const float* WrO = (const float*)d_in[13];
  const float* WmO = (const float*)d_in[14];
  const float* bmO = (const float*)d_in[15];
  const float* WzD = (const float*)d_in[16];
  const float* WrD = (const float*)d_in[17];
  const float* WmD = (const float*)d_in[18];
  const float* bmD = (const float*)d_in[19];
  const float* W1R = (const float*)d_in[20];
  const float* b1R = (const float*)d_in[21];
  const float* W2R = (const float*)d_in[22];
  const float* W1O = (const float*)d_in[23];
  const float* b1O = (const float*)d_in[24];
  const float* W2O = (const float*)d_in[25];
  const float* W1D = (const float*)d_in[26];
  const float* b1D = (const float*)d_in[27];
  const float* W2D = (const float*)d_in[28];
  const float* Tmp = (const float*)d_in[29];
  const float* GK  = (const float*)d_in[30];
  const float* GRK = (const float*)d_in[31];
  const float* GB  = (const float*)d_in[32];
  const float* WO  = (const float*)d_in[33];
  const int*   IDX = (const int*)d_in[34];

  float* tp = (float*)d_ws;  // 3*60 floats
  const int B = in_sizes[0] / 880;

  hipLaunchKernelGGL(temporal_kernel, dim3(1), dim3(64), 0, stream, Tmp, GK, GRK, GB, WO, IDX, tp);
  hipLaunchKernelGGL(ggnn_main, dim3((B + 3) / 4), dim3(256), 0, stream,
                     X, A, WgR, bgR, WgO, bgO, WgD, bgD,
                     WzR, WrR, WmR, bmR, WzO, WrO, WmO, bmO, WzD, WrD, WmD, bmD,
                     W1R, b1R, W2R, W1O, b1O, W2O, W1D, b1D, W2D,
                     tp, B, (float*)d_out);
}

// Round 10
// 1003.157 us; speedup vs baseline: 1.2118x; 1.2118x over previous
//
#include <hip/hip_runtime.h>
#include <hip/hip_bf16.h>
#include <math.h>

#define DEV __device__ __forceinline__

DEV float sigmoidf_(float x) { return 1.0f / (1.0f + __expf(-x)); }

#define R10(OP) OP(0) OP(1) OP(2) OP(3) OP(4) OP(5) OP(6) OP(7) OP(8) OP(9)
#define R11(OP) R10(OP) OP(10)

// Compact A staging (only the 240 used entries of the 22x22 matrix):
//   sA2[AROB + j]        = A[0][1+j]        j<10   (R <- O row)
//   sA2[AORB + i]        = A[1+i][0]        i<10   (O <- R col)
//   sA2[AODB + i*11 + j] = A[1+i][11+j]     10x11  (O <- D block)
//   sA2[ADOB + i*10 + j] = A[11+i][1+j]     11x10  (D <- O block)
#define AROB 0
#define AORB 16
#define AODB 32
#define ADOB 144
#define ANUM 256

// dots against compact-A (entries are wave-uniform broadcasts)
#define DOT_ARO() (sA2[AROB+0]*hO0 + sA2[AROB+1]*hO1 + sA2[AROB+2]*hO2 + sA2[AROB+3]*hO3 \
                 + sA2[AROB+4]*hO4 + sA2[AROB+5]*hO5 + sA2[AROB+6]*hO6 + sA2[AROB+7]*hO7 \
                 + sA2[AROB+8]*hO8 + sA2[AROB+9]*hO9)
#define DOT_AOD(i) (sA2[AODB+(i)*11+0]*hD0 + sA2[AODB+(i)*11+1]*hD1 + sA2[AODB+(i)*11+2]*hD2 \
                  + sA2[AODB+(i)*11+3]*hD3 + sA2[AODB+(i)*11+4]*hD4 + sA2[AODB+(i)*11+5]*hD5 \
                  + sA2[AODB+(i)*11+6]*hD6 + sA2[AODB+(i)*11+7]*hD7 + sA2[AODB+(i)*11+8]*hD8 \
                  + sA2[AODB+(i)*11+9]*hD9 + sA2[AODB+(i)*11+10]*hD10)
#define DOT_ADO(i) (sA2[ADOB+(i)*10+0]*hO0 + sA2[ADOB+(i)*10+1]*hO1 + sA2[ADOB+(i)*10+2]*hO2 \
                  + sA2[ADOB+(i)*10+3]*hO3 + sA2[ADOB+(i)*10+4]*hO4 + sA2[ADOB+(i)*10+5]*hO5 \
                  + sA2[ADOB+(i)*10+6]*hO6 + sA2[ADOB+(i)*10+7]*hO7 + sA2[ADOB+(i)*10+8]*hO8 \
                  + sA2[ADOB+(i)*10+9]*hO9)

DEV float gstep(float x, float h, const float* k, const float* rk, const float* bb) {
  const float z  = sigmoidf_(fmaf(x, k[0], bb[0]) + fmaf(h, rk[0], bb[3]));
  const float r  = sigmoidf_(fmaf(x, k[1], bb[1]) + fmaf(h, rk[1], bb[4]));
  const float hh = tanhf(fmaf(x, k[2], bb[2]) + r * fmaf(h, rk[2], bb[5]));
  return z * h + (1.f - z) * hh;
}

// 3 tiny sequential bidirectional GRU chains + softmax + gather -> tp[3][60]
__global__ void __launch_bounds__(64, 1)
temporal_kernel(const float* __restrict__ T, const float* __restrict__ GK,
                const float* __restrict__ GRK, const float* __restrict__ GB,
                const float* __restrict__ WO, const int* __restrict__ IDX,
                float* __restrict__ tp) {
  const int i = threadIdx.x;
  __shared__ float fb[3][75];
  __shared__ float gg[3][75];
  if (i < 3) {
    float k0[3], k1[3], rk0[3], rk1[3];
#pragma unroll
    for (int q = 0; q < 3; ++q) {
      k0[q]  = GK[i * 6 + q];      k1[q]  = GK[i * 6 + 3 + q];
      rk0[q] = GRK[i * 6 + q];     rk1[q] = GRK[i * 6 + 3 + q];
    }
    const float* B0 = GB + i * 12;
    const float* B1 = GB + i * 12 + 6;
    float h = 0.f;
    for (int s = 0; s < 75; ++s) { h = gstep(T[i * 75 + s], h, k0, rk0, B0); fb[i][s] = h; }
    h = 0.f;
    for (int s = 0; s < 75; ++s) { h = gstep(fb[i][74 - s], h, k1, rk1, B1); gg[i][s] = h; }
    const float wo = WO[i];
    float mx = -1e30f;
    for (int s = 0; s < 75; ++s) mx = fmaxf(mx, gg[i][s] * wo);
    float sum = 0.f;
    for (int s = 0; s < 75; ++s) { const float e = __expf(gg[i][s] * wo - mx); fb[i][s] = e; sum += e; }
    const float inv = 1.f / sum;
    for (int j = 0; j < 60; ++j) tp[i * 60 + j] = fb[i][IDX[j]] * inv;
  }
}

// 4 waves per 256-thread WG; wave w owns batch blockIdx.x*4+w with a PRIVATE
// LDS slice (no __syncthreads in hot path). amdgpu_waves_per_eu(4,4) PINS the
// allocator to the 4-waves/EU tier (128 VGPR) — the only tier this body has
// ever compiled spill-free at (rounds 4/8: VGPR=128, WRITE ~3 MB). Rounds
// 5/7/9 all spilled because the allocator freely chose 6-8 waves/EU tiers.
__global__ void __launch_bounds__(256)
__attribute__((amdgpu_waves_per_eu(4, 4)))
ggnn_main(
    const float* __restrict__ X, const float* __restrict__ A,
    const float* __restrict__ WgR, const float* __restrict__ bgR,
    const float* __restrict__ WgO, const float* __restrict__ bgO,
    const float* __restrict__ WgD, const float* __restrict__ bgD,
    const float* __restrict__ WzR, const float* __restrict__ WrR,
    const float* __restrict__ WmR, const float* __restrict__ bmR,
    const float* __restrict__ WzO, const float* __restrict__ WrO,
    const float* __restrict__ WmO, const float* __restrict__ bmO,
    const float* __restrict__ WzD, const float* __restrict__ WrD,
    const float* __restrict__ WmD, const float* __restrict__ bmD,
    const float* __restrict__ W1R, const float* __restrict__ b1R, const float* __restrict__ W2R,
    const float* __restrict__ W1O, const float* __restrict__ b1O, const float* __restrict__ W2O,
    const float* __restrict__ W1D, const float* __restrict__ b1D, const float* __restrict__ W2D,
    const float* __restrict__ tp, int B, float* __restrict__ out) {
  const int w = threadIdx.x >> 6;   // wave 0..3
  const int c = threadIdx.x & 63;   // lane = feature column
  const int b = blockIdx.x * 4 + w;

  __shared__ __align__(16) float smemAll[4 * 1920];
  __shared__ float sAAll[4 * ANUM];
  float* sm = smemAll + w * 1920;
  const float* sA2 = sAAll + w * ANUM;

  if (b >= B) return;

  const float* Xb = X + (size_t)b * 880;
  const float* Ab = A + (size_t)b * 484;
  for (int t = c; t < 880; t += 64) sm[t] = Xb[t];
  {
    float* sw = sAAll + w * ANUM;
    if (c < 10) {
      sw[AROB + c] = Ab[1 + c];            // A[0][1+c]
      sw[AORB + c] = Ab[(1 + c) * 22];     // A[1+c][0]
    }
    for (int t = c; t < 110; t += 64) {
      const int i = t / 11, j = t - i * 11;
      sw[AODB + t] = Ab[(1 + i) * 22 + 11 + j];
    }
    for (int t = c; t < 110; t += 64) {
      const int i = t / 10, j = t - i * 10;
      sw[ADOB + t] = Ab[(11 + i) * 22 + 1 + j];
    }
  }

  // ---------------- phase 0: h = tanh(Xg @ Wg + bg) ----------------
  float hR;
#define DECLHO(i) float hO##i;
  R10(DECLHO)
#undef DECLHO
#define DECLHD(i) float hD##i;
  R11(DECLHD)
#undef DECLHD
  {
    float aR = bgR[c], cO = bgO[c], cD = bgD[c];
#pragma unroll 4
    for (int k = 0; k < 40; ++k) {
      const float x = sm[k];
      aR = fmaf(x, WgR[k * 64 + c], aR);
      cO = fmaf(x, WgO[k * 64 + c], cO);
      cD = fmaf(x, WgD[k * 64 + c], cD);
    }
    hR = tanhf(aR);
#define DECLAO(i) float aO##i = cO;
    R10(DECLAO)
#undef DECLAO
#define DECLAD(i) float aD##i = cD;
    R11(DECLAD)
#undef DECLAD
#pragma unroll 2
    for (int k = 0; k < 30; ++k) {
      const float wo_ = WgO[(40 + k) * 64 + c];
      const float wd_ = WgD[(40 + k) * 64 + c];
#define AOSTEP(i) aO##i = fmaf(sm[(1 + i) * 40 + 10 + k], wo_, aO##i);
      R10(AOSTEP)
#undef AOSTEP
#define ADSTEP(i) aD##i = fmaf(sm[(11 + i) * 40 + 10 + k], wd_, aD##i);
      R11(ADSTEP)
#undef ADSTEP
    }
#define TANHO(i) hO##i = tanhf(aO##i);
    R10(TANHO)
#undef TANHO
#define TANHD(i) hD##i = tanhf(aD##i);
    R11(TANHD)
#undef TANHD
  }

  // ---------------- 3 GRU iterations ----------------
  for (int it = 0; it < 3; ++it) {
    // snapshot messages that depend on OLD hO (gate O overwrites hO)
    const float nR = DOT_ARO();
#define DECLND(i) const float nD##i = DOT_ADO(i);
    R11(DECLND)
#undef DECLND

    // ---- phase A: gate O (10 rows, K=192), region sm[0..1919] ----
#define STAGEO(i) sm[i * 192 + c] = hO##i; \
                  sm[i * 192 + 64 + c] = sA2[AORB + i] * hR; \
                  sm[i * 192 + 128 + c] = DOT_AOD(i);
    R10(STAGEO)
#undef STAGEO
    {
#define DECLZR(i) float az##i = 0.f, ar##i = 0.f;
      R10(DECLZR)
#undef DECLZR
#pragma unroll 2
      for (int k4 = 0; k4 < 192; k4 += 4) {
        const float wa0 = WzO[(k4 + 0) * 64 + c], wa1 = WzO[(k4 + 1) * 64 + c];
        const float wa2 = WzO[(k4 + 2) * 64 + c], wa3 = WzO[(k4 + 3) * 64 + c];
        const float wb0 = WrO[(k4 + 0) * 64 + c], wb1 = WrO[(k4 + 1) * 64 + c];
        const float wb2 = WrO[(k4 + 2) * 64 + c], wb3 = WrO[(k4 + 3) * 64 + c];
#define MSTEP(i) { const float4 v = *reinterpret_cast<const float4*>(&sm[i * 192 + k4]); \
        az##i = fmaf(v.x, wa0, az##i); az##i = fmaf(v.y, wa1, az##i); \
        az##i = fmaf(v.z, wa2, az##i); az##i = fmaf(v.w, wa3, az##i); \
        ar##i = fmaf(v.x, wb0, ar##i); ar##i = fmaf(v.y, wb1, ar##i); \
        ar##i = fmaf(v.z, wb2, ar##i); ar##i = fmaf(v.w, wb3, ar##i); }
        R10(MSTEP)
#undef MSTEP
      }
#define SIGZR(i) const float z##i = sigmoidf_(az##i); const float r##i = sigmoidf_(ar##i);
      R10(SIGZR)
#undef SIGZR
#define STAGEHR(i) sm[i * 192 + c] = hO##i * r##i;
      R10(STAGEHR)
#undef STAGEHR
#define DECLAM(i) float am##i = bmO[c];
      R10(DECLAM)
#undef DECLAM
#pragma unroll 2
      for (int k4 = 0; k4 < 192; k4 += 4) {
        const float w0 = WmO[(k4 + 0) * 64 + c], w1 = WmO[(k4 + 1) * 64 + c];
        const float w2 = WmO[(k4 + 2) * 64 + c], w3 = WmO[(k4 + 3) * 64 + c];
#define MSTEP(i) { const float4 v = *reinterpret_cast<const float4*>(&sm[i * 192 + k4]); \
        am##i = fmaf(v.x, w0, am##i); am##i = fmaf(v.y, w1, am##i); \
        am##i = fmaf(v.z, w2, am##i); am##i = fmaf(v.w, w3, am##i); }
        R10(MSTEP)
#undef MSTEP
      }
#define UPDO(i) hO##i = (1.f - z##i) * hO##i + z##i * tanhf(am##i);
      R10(UPDO)
#undef UPDO
    }

    // ---- phase B: gates D (11 rows, K=128, sm[0..1407]) + R (sm[1408..1535]) ----
#define STAGEDD(i) sm[i * 128 + c] = hD##i; \
                   sm[i * 128 + 64 + c] = nD##i;
    R11(STAGEDD)
#undef STAGEDD
    sm[1408 + c] = hR;
    sm[1472 + c] = nR;
    {
#define DECLZR(i) float az##i = 0.f, ar##i = 0.f;
      R11(DECLZR)
#undef DECLZR
      float azR = 0.f, arR = 0.f;
#pragma unroll 2
      for (int k4 = 0; k4 < 128; k4 += 4) {
        const float wa0 = WzD[(k4 + 0) * 64 + c], wa1 = WzD[(k4 + 1) * 64 + c];
        const float wa2 = WzD[(k4 + 2) * 64 + c], wa3 = WzD[(k4 + 3) * 64 + c];
        const float wb0 = WrD[(k4 + 0) * 64 + c], wb1 = WrD[(k4 + 1) * 64 + c];
        const float wb2 = WrD[(k4 + 2) * 64 + c], wb3 = WrD[(k4 + 3) * 64 + c];
#define MSTEP(i) { const float4 v = *reinterpret_cast<const float4*>(&sm[i * 128 + k4]); \
        az##i = fmaf(v.x, wa0, az##i); az##i = fmaf(v.y, wa1, az##i); \
        az##i = fmaf(v.z, wa2, az##i); az##i = fmaf(v.w, wa3, az##i); \
        ar##i = fmaf(v.x, wb0, ar##i); ar##i = fmaf(v.y, wb1, ar##i); \
        ar##i = fmaf(v.z, wb2, ar##i); ar##i = fmaf(v.w, wb3, ar##i); }
        R11(MSTEP)
#undef MSTEP
        const float wza0 = WzR[(k4 + 0) * 64 + c], wza1 = WzR[(k4 + 1) * 64 + c];
        const float wza2 = WzR[(k4 + 2) * 64 + c], wza3 = WzR[(k4 + 3) * 64 + c];
        const float wra0 = WrR[(k4 + 0) * 64 + c], wra1 = WrR[(k4 + 1) * 64 + c];
        const float wra2 = WrR[(k4 + 2) * 64 + c], wra3 = WrR[(k4 + 3) * 64 + c];
        const float4 vr = *reinterpret_cast<const float4*>(&sm[1408 + k4]);
        azR = fmaf(vr.x, wza0, azR); azR = fmaf(vr.y, wza1, azR);
        azR = fmaf(vr.z, wza2, azR); azR = fmaf(vr.w, wza3, azR);
        arR = fmaf(vr.x, wra0, arR); arR = fmaf(vr.y, wra1, arR);
        arR = fmaf(vr.z, wra2, arR); arR = fmaf(vr.w, wra3, arR);
      }
#define SIGZR(i) const float z##i = sigmoidf_(az##i); const float r##i = sigmoidf_(ar##i);
      R11(SIGZR)
#undef SIGZR
      const float zR_ = sigmoidf_(azR);
      const float rR_ = sigmoidf_(arR);
#define STAGEHR(i) sm[i * 128 + c] = hD##i * r##i;
      R11(STAGEHR)
#undef STAGEHR
      sm[1408 + c] = hR * rR_;
#define DECLAM(i) float am##i = bmD[c];
      R11(DECLAM)
#undef DECLAM
      float amR = bmR[c];
#pragma unroll 2
      for (int k4 = 0; k4 < 128; k4 += 4) {
        const float w0 = WmD[(k4 + 0) * 64 + c], w1 = WmD[(k4 + 1) * 64 + c];
        const float w2 = WmD[(k4 + 2) * 64 + c], w3 = WmD[(k4 + 3) * 64 + c];
#define MSTEP(i) { const float4 v = *reinterpret_cast<const float4*>(&sm[i * 128 + k4]); \
        am##i = fmaf(v.x, w0, am##i); am##i = fmaf(v.y, w1, am##i); \
        am##i = fmaf(v.z, w2, am##i); am##i = fmaf(v.w, w3, am##i); }
        R11(MSTEP)
#undef MSTEP
        const float wm0 = WmR[(k4 + 0) * 64 + c], wm1 = WmR[(k4 + 1) * 64 + c];
        const float wm2 = WmR[(k4 + 2) * 64 + c], wm3 = WmR[(k4 + 3) * 64 + c];
        const float4 vr = *reinterpret_cast<const float4*>(&sm[1408 + k4]);
        amR = fmaf(vr.x, wm0, amR); amR = fmaf(vr.y, wm1, amR);
        amR = fmaf(vr.z, wm2, amR); amR = fmaf(vr.w, wm3, amR);
      }
#define UPDD(i) hD##i = (1.f - z##i) * hD##i + z##i * tanhf(am##i);
      R11(UPDD)
#undef UPDD
      hR = (1.f - zR_) * hR + zR_ * tanhf(amR);
    }
  }

  // ---------------- scores ----------------
  sm[c] = hR;
#define STASH_O(i) sm[(1 + i) * 64 + c] = hO##i;
  R10(STASH_O)
#undef STASH_O
#define STASH_D(i) sm[(11 + i) * 64 + c] = hD##i;
  R11(STASH_D)
#undef STASH_D

  const int g = c >> 4;    // row-group 0..3
  const int c1 = c & 15;   // hidden-1 column
  float pR = 0.f, pO = 0.f, pD = 0.f;
  for (int rr = g; rr < 22; rr += 4) {
    const float* W1; const float* b1; const float* W2;
    if (rr == 0)      { W1 = W1R; b1 = b1R; W2 = W2R; }
    else if (rr < 11) { W1 = W1O; b1 = b1O; W2 = W2O; }
    else              { W1 = W1D; b1 = b1D; W2 = W2D; }
    float a = b1[c1];
#pragma unroll 8
    for (int kk = 0; kk < 64; ++kk) {
      const int k = (kk + (g << 4)) & 63;  // stagger to dodge LDS bank aliasing
      a = fmaf(sm[rr * 64 + k], W1[k * 16 + c1], a);
    }
    const float t = tanhf(a) * W2[c1];
    if (rr == 0) pR += t;
    else if (rr < 11) pO += t;
    else pD += t;
  }
#pragma unroll
  for (int off = 32; off >= 1; off >>= 1) {
    pR += __shfl_xor(pR, off, 64);
    pO += __shfl_xor(pO, off, 64);
    pD += __shfl_xor(pD, off, 64);
  }
  if (c < 60) {
    out[(size_t)b * 60 + c] = pR * tp[c] + pO * tp[60 + c] + pD * tp[120 + c];
  }
}

extern "C" void kernel_launch(void* const* d_in, const int* in_sizes, int n_in,
                              void* d_out, int out_size, void* d_ws, size_t ws_size,
                              hipStream_t stream) {
  const float* X   = (const float*)d_in[0];
  const float* A   = (const float*)d_in[1];
  const float* WgR = (const float*)d_in[2];
  const float* bgR = (const float*)d_in[3];
  const float* WgO = (const float*)d_in[4];
  const float* bgO = (const float*)d_in[5];
  const float* WgD = (const float*)d_in[6];
  const float* bgD = (const float*)d_in[7];
  const float* WzR = (const float*)d_in[8];
  const float* WrR = (const float*)d_in[9];
  const float* WmR = (const float*)d_in[10];
  const float* bmR = (const float*)d_in[11];
  const float* WzO = (const float*)d_in[12];
  const float* WrO = (const float*)d_in[13];
  const float* WmO = (const float*)d_in[14];
  const float* bmO = (const float*)d_in[15];
  const float* WzD = (const float*)d_in[16];
  const float* WrD = (const float*)d_in[17];
  const float* WmD = (const float*)d_in[18];
  const float* bmD = (const float*)d_in[19];
  const float* W1R = (const float*)d_in[20];
  const float* b1R = (const float*)d_in[21];
  const float* W2R = (const float*)d_in[22];
  const float* W1O = (const float*)d_in[23];
  const float* b1O = (const float*)d_in[24];
  const float* W2O = (const float*)d_in[25];
  const float* W1D = (const float*)d_in[26];
  const float* b1D = (const float*)d_in[27];
  const float* W2D = (const float*)d_in[28];
  const float* Tmp = (const float*)d_in[29];
  const float* GK  = (const float*)d_in[30];
  const float* GRK = (const float*)d_in[31];
  const float* GB  = (const float*)d_in[32];
  const float* WO  = (const float*)d_in[33];
  const int*   IDX = (const int*)d_in[34];

  float* tp = (float*)d_ws;  // 3*60 floats
  const int B = in_sizes[0] / 880;

  hipLaunchKernelGGL(temporal_kernel, dim3(1), dim3(64), 0, stream, Tmp, GK, GRK, GB, WO, IDX, tp);
  hipLaunchKernelGGL(ggnn_main, dim3((B + 3) / 4), dim3(256), 0, stream,
                     X, A, WgR, bgR, WgO, bgO, WgD, bgD,
                     WzR, WrR, WmR, bmR, WzO, WrO, WmO, bmO, WzD, WrD, WmD, bmD,
                     W1R, b1R, W2R, W1O, b1O, W2O, W1D, b1D, W2D,
                     tp, B, (float*)d_out);
}